// Round 10
// baseline (215.603 us; speedup 1.0000x reference)
//
#include <hip/hip_runtime.h>
#include <stdint.h>

#define NN 50000
#define NE 800000
#define D  128
#define NEG_INIT -1e9f
#define NS 4                              // src slices (12500 nodes = 3.2 MB bf16 -> fits 4 MiB XCD L2)
#define SLICE 12500
#define CAPS 20                           // per-(node,slice) capacity; Poisson(4), P(>20)~1e-9
#define OVF_CAP 131072

// ---------------- ws layout (int offsets) ----------------
#define CNT_OFF     64                    // NN*NS counters
#define OVF_CNT_OFF 200064                // overflow counter
#define OVF_OFF     200068                // OVF_CAP pairs (dst, entry)
#define BKT_OFF     462336                // NN*NS*CAPS packed entries: (w_bf16<<16)|src
#define XBF_OFF     4462336               // NN*D bf16 x = 3.2M ints
#define WBF_OFF     7662336               // w1+w2 bf16 = 16384 ints
// total: 7,678,720 ints = 30.7 MB (< 32.4 MB proven available)

#define NBLKC 782                         // ceil((NN*NS+1)/256) zero-blocks
#define HSTRIDE 136                       // LDS row stride in ushorts (272 B, 2-way banks = free)

typedef __attribute__((ext_vector_type(8))) short short8;
typedef __attribute__((ext_vector_type(4))) float float4v;

// ---------------- bf16 helpers ----------------
__device__ __forceinline__ float b2f(uint16_t u) {
    union { uint32_t u; float f; } v; v.u = ((uint32_t)u) << 16; return v.f;
}
__device__ __forceinline__ uint16_t f2b(float f) {
    union { float f; uint32_t u; } v; v.f = f;
    uint32_t r = v.u + 0x7fffu + ((v.u >> 16) & 1u);   // RNE
    return (uint16_t)(r >> 16);
}

// ---------------- per-block inline dtype probe ----------------
__device__ __forceinline__ void block_probe(const uint16_t* __restrict__ xraw,
                                            const int* __restrict__ eraw,
                                            int* sflags) {
    int t = threadIdx.x;
    if (t < 64) {                                   // wave 0 only
        float v0 = b2f(xraw[2 * t]);
        float v1 = b2f(xraw[2 * t + 1]);
        int bad = (!(v0 > -1e4f && v0 < 1e4f)) || (!(v1 > -1e4f && v1 < 1e4f));
        unsigned long long bm = __ballot(bad);
        int nz = (t < 32) ? (eraw[2 * t + 1] != 0) : 0;
        unsigned long long im = __ballot(nz);
        if (t == 0) { sflags[0] = bm ? 1 : 0; sflags[1] = im ? 0 : 1; }
    }
    __syncthreads();
}

// ---------------- fused prep: x->bf16 | w1,w2->bf16 | zero counters ----------------
// grid = 6250 (x) + 32 (w) + NBLKC (zero) = 7064 blocks
__global__ __launch_bounds__(256) void prep_kernel(
    const uint16_t* __restrict__ xraw,
    const int*      __restrict__ eraw,
    const uint16_t* __restrict__ w1raw,
    const uint16_t* __restrict__ w2raw,
    int* __restrict__ ws)
{
    __shared__ int sflags[2];
    block_probe(xraw, eraw, sflags);
    const int f32 = sflags[0];

    int bid = blockIdx.x;
    if (bid < 6250) {
        int i4 = (bid * 256 + threadIdx.x) * 4;          // covers NN*D = 6.4M exactly
        ushort* dst = (ushort*)(ws + XBF_OFF);
        if (f32) {
            float4 v = *(const float4*)((const float*)xraw + i4);
            ushort4 o; o.x = f2b(v.x); o.y = f2b(v.y); o.z = f2b(v.z); o.w = f2b(v.w);
            *(ushort4*)(dst + i4) = o;
        } else {
            *(ushort4*)(dst + i4) = *(const ushort4*)(xraw + i4);
        }
    } else if (bid < 6282) {
        int i4 = ((bid - 6250) * 256 + threadIdx.x) * 4; // 0..32764
        const uint16_t* src = (i4 < 16384) ? w1raw : w2raw;
        int off = i4 & 16383;
        ushort* dst = (ushort*)(ws + WBF_OFF);
        if (f32) {
            float4 v = *(const float4*)((const float*)src + off);
            ushort4 o; o.x = f2b(v.x); o.y = f2b(v.y); o.z = f2b(v.z); o.w = f2b(v.w);
            *(ushort4*)(dst + i4) = o;
        } else {
            *(ushort4*)(dst + i4) = *(const ushort4*)(src + off);
        }
    } else {
        int i = (bid - 6282) * 256 + threadIdx.x;
        if (i < NN * NS) ws[CNT_OFF + i] = 0;
        if (i == NN * NS) ws[OVF_CNT_OFF] = 0;
    }
}

// ---------------- direct sliced-bucket fill ----------------
__global__ __launch_bounds__(256) void fill_kernel(
    const uint16_t* __restrict__ xraw,
    const int*      __restrict__ eraw,
    const uint16_t* __restrict__ ewraw,
    int* __restrict__ ws)
{
    __shared__ int sflags[2];
    block_probe(xraw, eraw, sflags);
    const int f32 = sflags[0], i64 = sflags[1];

    int e = blockIdx.x * 256 + threadIdx.x;              // grid 3125 exact
    int src, dst;
    if (i64) {
        const long long* e64 = (const long long*)eraw;
        src = (int)e64[e];
        dst = (int)e64[NE + e];
    } else {
        src = eraw[e];
        dst = eraw[NE + e];
    }
    if ((unsigned)src >= NN || (unsigned)dst >= NN) return;
    uint w = f32 ? (uint)f2b(((const float*)ewraw)[e]) : (uint)ewraw[e];
    uint entry = (w << 16) | (uint)src;
    int s = src / SLICE;                                 // 0..3
    int cell = dst * NS + s;
    int slot = atomicAdd(ws + CNT_OFF + cell, 1);
    if (slot < CAPS) {
        ((uint*)(ws + BKT_OFF))[(size_t)cell * CAPS + slot] = entry;
    } else {
        int o = atomicAdd(ws + OVF_CNT_OFF, 1);
        if (o < OVF_CAP) {
            ws[OVF_OFF + 2 * o]     = dst;
            ws[OVF_OFF + 2 * o + 1] = (int)entry;
        }
    }
}

// ---------------- fused gather-max + MFMA MLP, slice-phased ----------------
// 16 nodes/block, 4 waves; wave owns 4 nodes (lane = dim pair). Outer loop over
// src-slices with block-wide sync: all co-resident blocks hit the SAME 3.2 MB
// x-slice -> L2-resident gathers. Windows: unmasked chunks-of-4 with idempotent
// overlap (cnt>=4) / masked 4-window (cnt<4).
// A[m=lane&15][k=quad*8+j]; C/D: col=lane&15, row=quad*4+reg.
__global__ __launch_bounds__(256) void gmlp_kernel(
    const uint16_t* __restrict__ xraw,
    const int*      __restrict__ eraw,
    const uint16_t* __restrict__ b1raw,
    const uint16_t* __restrict__ b2raw,
    const uint16_t* __restrict__ epsraw,
    const int* __restrict__ ws,
    uint16_t* __restrict__ outraw)
{
    __shared__ int    sflags[2];
    __shared__ uint   tl[16 * (HSTRIDE / 2)];   // t tile, 68 uints/row
    __shared__ ushort hl[16 * HSTRIDE];         // hidden tile

    block_probe(xraw, eraw, sflags);
    const int f32 = sflags[0];

    const int tid  = threadIdx.x;
    const int wave = tid >> 6;
    const int lane = tid & 63;
    const int m    = lane & 15;
    const int quad = lane >> 4;
    const int node0 = blockIdx.x * 16;

    const ushort* w1b = (const ushort*)(ws + WBF_OFF);
    const ushort* w2b = w1b + 16384;
    const uint*   xbf = (const uint*)(ws + XBF_OFF);
    const uint*   bkt = (const uint*)(ws + BKT_OFF);

    const float eps1 = 1.0f + (f32 ? ((const float*)epsraw)[0] : b2f(epsraw[0]));

    float acc0[4], acc1[4];
    int   tot[4];
    int   ovf_any = 0;
    #pragma unroll
    for (int j = 0; j < 4; ++j) { acc0[j] = NEG_INIT; acc1[j] = NEG_INIT; tot[j] = 0; }

    // slice-phased gather
    for (int s = 0; s < NS; ++s) {
        #pragma unroll
        for (int j = 0; j < 4; ++j) {
            int n = node0 + wave * 4 + j;
            int cell = n * NS + s;
            int cr = ws[CNT_OFF + cell];                 // wave-uniform
            tot[j] += cr;
            if (cr > CAPS) ovf_any = 1;
            int cc = (cr < CAPS) ? cr : CAPS;
            const uint* brow = bkt + (size_t)cell * CAPS;

            if (cc >= 4) {
                int i = 0;
                while (true) {
                    uint e0 = brow[i], e1 = brow[i + 1], e2 = brow[i + 2], e3 = brow[i + 3];
                    uint v0 = xbf[(e0 & 0xffffu) * 64 + lane];
                    uint v1 = xbf[(e1 & 0xffffu) * 64 + lane];
                    uint v2 = xbf[(e2 & 0xffffu) * 64 + lane];
                    uint v3 = xbf[(e3 & 0xffffu) * 64 + lane];
                    float w0 = b2f((uint16_t)(e0 >> 16)), w1v = b2f((uint16_t)(e1 >> 16));
                    float w2v = b2f((uint16_t)(e2 >> 16)), w3 = b2f((uint16_t)(e3 >> 16));
                    float q0 = fmaxf(b2f((uint16_t)v0) * w0, b2f((uint16_t)v1) * w1v);
                    float q1 = fmaxf(b2f((uint16_t)v2) * w2v, b2f((uint16_t)v3) * w3);
                    acc0[j] = fmaxf(acc0[j], fmaxf(q0, q1));
                    float r0 = fmaxf(b2f((uint16_t)(v0 >> 16)) * w0, b2f((uint16_t)(v1 >> 16)) * w1v);
                    float r1 = fmaxf(b2f((uint16_t)(v2 >> 16)) * w2v, b2f((uint16_t)(v3 >> 16)) * w3);
                    acc1[j] = fmaxf(acc1[j], fmaxf(r0, r1));
                    i += 4;
                    if (i >= cc) break;
                    if (i + 4 > cc) i = cc - 4;          // idempotent overlap window
                }
            } else if (cc > 0) {
                // masked 4-window (tail slots hold poison; 0xAAAA row is in-bounds)
                uint e0 = brow[0], e1 = brow[1], e2 = brow[2], e3 = brow[3];
                uint ee[4] = {e0, e1, e2, e3};
                #pragma unroll
                for (int u = 0; u < 4; ++u) {
                    uint v = xbf[(ee[u] & 0xffffu) * 64 + lane];
                    float w  = b2f((uint16_t)(ee[u] >> 16));
                    bool ok = u < cc;
                    float p0 = b2f((uint16_t)v) * w;
                    float p1 = b2f((uint16_t)(v >> 16)) * w;
                    acc0[j] = fmaxf(acc0[j], ok ? p0 : NEG_INIT);
                    acc1[j] = fmaxf(acc1[j], ok ? p1 : NEG_INIT);
                }
            }
        }
        __syncthreads();                                 // keep block slice-phased
    }

    // overflow edges (exactness insurance; statistically never taken)
    if (ovf_any) {
        int novf = ws[OVF_CNT_OFF];
        if (novf > OVF_CAP) novf = OVF_CAP;
        for (int o = 0; o < novf; ++o) {
            int dsto = ws[OVF_OFF + 2 * o];
            #pragma unroll
            for (int j = 0; j < 4; ++j) {
                int n = node0 + wave * 4 + j;
                if (dsto == n) {
                    uint e0 = (uint)ws[OVF_OFF + 2 * o + 1];
                    uint v  = xbf[(e0 & 0xffff) * 64 + lane];
                    float w = b2f((uint16_t)(e0 >> 16));
                    acc0[j] = fmaxf(acc0[j], b2f((uint16_t)v) * w);
                    acc1[j] = fmaxf(acc1[j], b2f((uint16_t)(v >> 16)) * w);
                }
            }
        }
    }

    // t = (1+eps)x + agg -> LDS tile
    #pragma unroll
    for (int j = 0; j < 4; ++j) {
        int nl = wave * 4 + j;
        int n  = node0 + nl;
        float mx = acc0[j], my = acc1[j];
        if (tot[j] == 0) { mx = 0.f; my = 0.f; }         // isolated node -> 0
        uint xv = xbf[(size_t)n * 64 + lane];            // self term (cache-hot)
        float t0 = eps1 * b2f((uint16_t)xv) + mx;
        float t1 = eps1 * b2f((uint16_t)(xv >> 16)) + my;
        tl[nl * (HSTRIDE / 2) + lane] = (uint)f2b(t0) | ((uint)f2b(t1) << 16);
    }
    __syncthreads();

    // A frags from LDS t tile
    short8 a[4];
    {
        const ushort* arow = (const ushort*)tl + m * HSTRIDE + quad * 8;
        #pragma unroll
        for (int kb = 0; kb < 4; ++kb) a[kb] = *(const short8*)(arow + kb * 32);
    }

    // GEMM1 + bias + LeakyReLU -> hl
    #pragma unroll
    for (int t = 0; t < 2; ++t) {
        int ct = wave * 2 + t;
        float4v c = {0.f, 0.f, 0.f, 0.f};
        const ushort* brow = w1b + (size_t)(ct * 16 + m) * 128 + quad * 8;
        #pragma unroll
        for (int kb = 0; kb < 4; ++kb)
            c = __builtin_amdgcn_mfma_f32_16x16x32_bf16(a[kb], *(const short8*)(brow + kb * 32), c, 0, 0, 0);
        float bias = f32 ? ((const float*)b1raw)[ct * 16 + m] : b2f(b1raw[ct * 16 + m]);
        #pragma unroll
        for (int r = 0; r < 4; ++r) {
            float v = c[r] + bias;
            v = (v >= 0.f) ? v : 0.01f * v;
            hl[(quad * 4 + r) * HSTRIDE + ct * 16 + m] = f2b(v);
        }
    }
    __syncthreads();

    // A frags for GEMM2 from hl
    short8 ah[4];
    {
        const ushort* hrow = hl + m * HSTRIDE + quad * 8;
        #pragma unroll
        for (int kb = 0; kb < 4; ++kb) ah[kb] = *(const short8*)(hrow + kb * 32);
    }

    // GEMM2 + bias -> out
    #pragma unroll
    for (int t = 0; t < 2; ++t) {
        int ct = wave * 2 + t;
        float4v c = {0.f, 0.f, 0.f, 0.f};
        const ushort* brow = w2b + (size_t)(ct * 16 + m) * 128 + quad * 8;
        #pragma unroll
        for (int kb = 0; kb < 4; ++kb)
            c = __builtin_amdgcn_mfma_f32_16x16x32_bf16(ah[kb], *(const short8*)(brow + kb * 32), c, 0, 0, 0);
        float bias = f32 ? ((const float*)b2raw)[ct * 16 + m] : b2f(b2raw[ct * 16 + m]);
        #pragma unroll
        for (int r = 0; r < 4; ++r) {
            float v = c[r] + bias;
            size_t o = (size_t)(node0 + quad * 4 + r) * 128 + ct * 16 + m;
            if (f32) ((float*)outraw)[o] = v;
            else     outraw[o] = f2b(v);
        }
    }
}

// ================= host =================
extern "C" void kernel_launch(void* const* d_in, const int* in_sizes, int n_in,
                              void* d_out, int out_size, void* d_ws, size_t ws_size,
                              hipStream_t stream) {
    const uint16_t* x    = (const uint16_t*)d_in[0];
    const int*      eidx = (const int*)     d_in[1];
    const uint16_t* ew   = (const uint16_t*)d_in[2];
    const uint16_t* w1   = (const uint16_t*)d_in[3];
    const uint16_t* b1   = (const uint16_t*)d_in[4];
    const uint16_t* w2   = (const uint16_t*)d_in[5];
    const uint16_t* b2   = (const uint16_t*)d_in[6];
    const uint16_t* eps  = (const uint16_t*)d_in[7];
    uint16_t*       out  = (uint16_t*)d_out;
    int* ws = (int*)d_ws;

    prep_kernel<<<6250 + 32 + NBLKC, 256, 0, stream>>>(x, eidx, w1, w2, ws);
    fill_kernel<<<NE / 256, 256, 0, stream>>>(x, eidx, ew, ws);
    gmlp_kernel<<<NN / 16, 256, 0, stream>>>(x, eidx, b1, b2, eps, ws, out);
}

// Round 11
// 202.344 us; speedup vs baseline: 1.0655x; 1.0655x over previous
//
#include <hip/hip_runtime.h>
#include <stdint.h>

#define NN 50000
#define NE 800000
#define D  128
#define NEG_INIT -1e9f
#define CAP 64                            // bucket capacity per node (Poisson(16); P(deg>64)~1e-19)
#define OVF_CAP 131072

// ---------------- ws layout (int offsets) ----------------
#define CNT_OFF     64                    // NN counters (+1 overflow counter right after)
#define OVF_CNT_OFF 50064                 // overflow counter (zeroed by same memset)
#define OVF_OFF     50068                 // OVF_CAP pairs (dst, entry)
#define BKT_OFF     312320                // NN*CAP packed entries: (w_bf16<<16)|src
#define XBF_OFF     3512320               // NN*D bf16 x = 3.2M ints
#define WBF_OFF     6712320               // w1+w2 bf16 = 16384 ints
// total: 6,728,704 ints = 26.9 MB (< 32.4 MB proven available)

#define HSTRIDE 136                       // LDS row stride in ushorts (272 B, 2-way banks = free)

// fused prep+fill block ranges
#define FILL_BLKS 3125                    // NE/256
#define PX_BLKS   6250                    // NN*D/1024
#define PW_BLKS   32

typedef __attribute__((ext_vector_type(8))) short short8;
typedef __attribute__((ext_vector_type(4))) float float4v;

// ---------------- bf16 helpers ----------------
__device__ __forceinline__ float b2f(uint16_t u) {
    union { uint32_t u; float f; } v; v.u = ((uint32_t)u) << 16; return v.f;
}
__device__ __forceinline__ uint16_t f2b(float f) {
    union { float f; uint32_t u; } v; v.f = f;
    uint32_t r = v.u + 0x7fffu + ((v.u >> 16) & 1u);   // RNE
    return (uint16_t)(r >> 16);
}

// ---------------- per-block inline dtype probe (load-bearing; rounds 2-9) ----------------
__device__ __forceinline__ void block_probe(const uint16_t* __restrict__ xraw,
                                            const int* __restrict__ eraw,
                                            int* sflags) {
    int t = threadIdx.x;
    if (t < 64) {                                   // wave 0 only
        float v0 = b2f(xraw[2 * t]);
        float v1 = b2f(xraw[2 * t + 1]);
        int bad = (!(v0 > -1e4f && v0 < 1e4f)) || (!(v1 > -1e4f && v1 < 1e4f));
        unsigned long long bm = __ballot(bad);
        int nz = (t < 32) ? (eraw[2 * t + 1] != 0) : 0;
        unsigned long long im = __ballot(nz);
        if (t == 0) { sflags[0] = bm ? 1 : 0; sflags[1] = im ? 0 : 1; }
    }
    __syncthreads();
}

// ---------------- fused fill + prep_x + prep_w ----------------
// fill blocks FIRST (latency-bound atomics start early; prep_x streaming
// overlaps on the same CUs). Counters pre-zeroed by hipMemsetAsync.
__global__ __launch_bounds__(256) void prep_fill_kernel(
    const uint16_t* __restrict__ xraw,
    const int*      __restrict__ eraw,
    const uint16_t* __restrict__ ewraw,
    const uint16_t* __restrict__ w1raw,
    const uint16_t* __restrict__ w2raw,
    int* __restrict__ ws)
{
    __shared__ int sflags[2];
    block_probe(xraw, eraw, sflags);
    const int f32 = sflags[0], i64 = sflags[1];

    int bid = blockIdx.x;
    if (bid < FILL_BLKS) {
        // ---- edge fill: one packed 4 B entry per edge ----
        int e = bid * 256 + threadIdx.x;
        int src, dst;
        if (i64) {
            const long long* e64 = (const long long*)eraw;
            src = (int)e64[e];
            dst = (int)e64[NE + e];
        } else {
            src = eraw[e];
            dst = eraw[NE + e];
        }
        if ((unsigned)src >= NN || (unsigned)dst >= NN) return;
        uint w = f32 ? (uint)f2b(((const float*)ewraw)[e]) : (uint)ewraw[e];
        uint entry = (w << 16) | (uint)src;
        int slot = atomicAdd(ws + CNT_OFF + dst, 1);
        if (slot < CAP) {
            ((uint*)(ws + BKT_OFF))[(size_t)dst * CAP + slot] = entry;
        } else {
            int o = atomicAdd(ws + OVF_CNT_OFF, 1);
            if (o < OVF_CAP) {
                ws[OVF_OFF + 2 * o]     = dst;
                ws[OVF_OFF + 2 * o + 1] = (int)entry;
            }
        }
    } else if (bid < FILL_BLKS + PX_BLKS) {
        // ---- x -> bf16 table ----
        int i4 = ((bid - FILL_BLKS) * 256 + threadIdx.x) * 4;   // covers NN*D exactly
        ushort* dst = (ushort*)(ws + XBF_OFF);
        if (f32) {
            float4 v = *(const float4*)((const float*)xraw + i4);
            ushort4 o; o.x = f2b(v.x); o.y = f2b(v.y); o.z = f2b(v.z); o.w = f2b(v.w);
            *(ushort4*)(dst + i4) = o;
        } else {
            *(ushort4*)(dst + i4) = *(const ushort4*)(xraw + i4);
        }
    } else {
        // ---- w1,w2 -> bf16 table ----
        int i4 = ((bid - FILL_BLKS - PX_BLKS) * 256 + threadIdx.x) * 4; // 0..32764
        const uint16_t* src = (i4 < 16384) ? w1raw : w2raw;
        int off = i4 & 16383;
        ushort* dst = (ushort*)(ws + WBF_OFF);
        if (f32) {
            float4 v = *(const float4*)((const float*)src + off);
            ushort4 o; o.x = f2b(v.x); o.y = f2b(v.y); o.z = f2b(v.z); o.w = f2b(v.w);
            *(ushort4*)(dst + i4) = o;
        } else {
            *(ushort4*)(dst + i4) = *(const ushort4*)(src + off);
        }
    }
}

// ---------------- fused gather-max + MFMA MLP (exact r8 structure, best measured) ----------------
// 16 nodes/block, 4 waves; wave gathers 4 nodes (lane = dim pair), unroll-16
// with uint4 bucket-entry loads (16 outstanding row-gathers). Then MFMA.
// A[m=lane&15][k=quad*8+j]; C/D: col=lane&15, row=quad*4+reg.
__global__ __launch_bounds__(256) void gmlp_kernel(
    const uint16_t* __restrict__ xraw,
    const int*      __restrict__ eraw,
    const uint16_t* __restrict__ b1raw,
    const uint16_t* __restrict__ b2raw,
    const uint16_t* __restrict__ epsraw,
    const int* __restrict__ ws,
    uint16_t* __restrict__ outraw)
{
    __shared__ int    sflags[2];
    __shared__ uint   tl[16 * (HSTRIDE / 2)];   // t tile, 68 uints/row
    __shared__ ushort hl[16 * HSTRIDE];         // hidden tile

    block_probe(xraw, eraw, sflags);
    const int f32 = sflags[0];

    const int tid  = threadIdx.x;
    const int wave = tid >> 6;
    const int lane = tid & 63;
    const int m    = lane & 15;
    const int quad = lane >> 4;
    const int node0 = blockIdx.x * 16;

    const ushort* w1b = (const ushort*)(ws + WBF_OFF);
    const ushort* w2b = w1b + 16384;
    const uint*   xbf = (const uint*)(ws + XBF_OFF);
    const uint*   bkt = (const uint*)(ws + BKT_OFF);

    const float eps1 = 1.0f + (f32 ? ((const float*)epsraw)[0] : b2f(epsraw[0]));

    // gather phase: 4 nodes per wave, lane covers dims (2*lane, 2*lane+1)
    for (int j = 0; j < 4; ++j) {
        int nl = wave * 4 + j;
        int n  = node0 + nl;
        int cnt_raw = ws[CNT_OFF + n];
        int cnt = (cnt_raw < CAP) ? cnt_raw : CAP;

        float m0[16], m1[16];
        #pragma unroll
        for (int u = 0; u < 16; ++u) { m0[u] = NEG_INIT; m1[u] = NEG_INIT; }

        const uint* brow = bkt + (size_t)n * CAP;
        for (int i = 0; i < cnt; i += 16) {
            uint4 q[4];
            #pragma unroll
            for (int qq = 0; qq < 4; ++qq) q[qq] = *(const uint4*)(brow + i + qq * 4);
            #pragma unroll
            for (int u = 0; u < 16; ++u) {
                uint e0 = ((const uint*)q)[u];
                bool ok = (i + u) < cnt;
                uint idx = ok ? (e0 & 0xffffu) : 0u;      // masked lanes gather row 0 (hot)
                uint v = xbf[idx * 64 + lane];
                float w  = b2f((uint16_t)(e0 >> 16));
                float p0 = b2f((uint16_t)v) * w;
                float p1 = b2f((uint16_t)(v >> 16)) * w;
                m0[u] = fmaxf(m0[u], ok ? p0 : NEG_INIT);
                m1[u] = fmaxf(m1[u], ok ? p1 : NEG_INIT);
            }
        }
        // overflow edges (exactness insurance; statistically never taken)
        if (cnt_raw > CAP) {
            int novf = ws[OVF_CNT_OFF];
            if (novf > OVF_CAP) novf = OVF_CAP;
            for (int o = 0; o < novf; ++o) {
                if (ws[OVF_OFF + 2 * o] == n) {
                    uint e0 = (uint)ws[OVF_OFF + 2 * o + 1];
                    uint v  = xbf[(e0 & 0xffff) * 64 + lane];
                    float w = b2f((uint16_t)(e0 >> 16));
                    m0[0] = fmaxf(m0[0], b2f((uint16_t)v) * w);
                    m1[0] = fmaxf(m1[0], b2f((uint16_t)(v >> 16)) * w);
                }
            }
        }
        #pragma unroll
        for (int u = 8; u > 0; u >>= 1)
            #pragma unroll
            for (int v2 = 0; v2 < u; ++v2) {
                m0[v2] = fmaxf(m0[v2], m0[v2 + u]);
                m1[v2] = fmaxf(m1[v2], m1[v2 + u]);
            }
        float mx = m0[0], my = m1[0];
        if (cnt_raw == 0) { mx = 0.f; my = 0.f; }        // isolated node -> 0

        // self term from bf16 table (cache-hot)
        uint xv = xbf[(size_t)n * 64 + lane];
        float t0 = eps1 * b2f((uint16_t)xv) + mx;
        float t1 = eps1 * b2f((uint16_t)(xv >> 16)) + my;
        tl[nl * (HSTRIDE / 2) + lane] = (uint)f2b(t0) | ((uint)f2b(t1) << 16);
    }
    __syncthreads();

    // A frags from LDS t tile
    short8 a[4];
    {
        const ushort* arow = (const ushort*)tl + m * HSTRIDE + quad * 8;
        #pragma unroll
        for (int kb = 0; kb < 4; ++kb) a[kb] = *(const short8*)(arow + kb * 32);
    }

    // GEMM1 + bias + LeakyReLU -> hl
    #pragma unroll
    for (int t = 0; t < 2; ++t) {
        int ct = wave * 2 + t;
        float4v c = {0.f, 0.f, 0.f, 0.f};
        const ushort* brow = w1b + (size_t)(ct * 16 + m) * 128 + quad * 8;
        #pragma unroll
        for (int kb = 0; kb < 4; ++kb)
            c = __builtin_amdgcn_mfma_f32_16x16x32_bf16(a[kb], *(const short8*)(brow + kb * 32), c, 0, 0, 0);
        float bias = f32 ? ((const float*)b1raw)[ct * 16 + m] : b2f(b1raw[ct * 16 + m]);
        #pragma unroll
        for (int r = 0; r < 4; ++r) {
            float v = c[r] + bias;
            v = (v >= 0.f) ? v : 0.01f * v;
            hl[(quad * 4 + r) * HSTRIDE + ct * 16 + m] = f2b(v);
        }
    }
    __syncthreads();

    // A frags for GEMM2 from hl
    short8 ah[4];
    {
        const ushort* hrow = hl + m * HSTRIDE + quad * 8;
        #pragma unroll
        for (int kb = 0; kb < 4; ++kb) ah[kb] = *(const short8*)(hrow + kb * 32);
    }

    // GEMM2 + bias -> out
    #pragma unroll
    for (int t = 0; t < 2; ++t) {
        int ct = wave * 2 + t;
        float4v c = {0.f, 0.f, 0.f, 0.f};
        const ushort* brow = w2b + (size_t)(ct * 16 + m) * 128 + quad * 8;
        #pragma unroll
        for (int kb = 0; kb < 4; ++kb)
            c = __builtin_amdgcn_mfma_f32_16x16x32_bf16(ah[kb], *(const short8*)(brow + kb * 32), c, 0, 0, 0);
        float bias = f32 ? ((const float*)b2raw)[ct * 16 + m] : b2f(b2raw[ct * 16 + m]);
        #pragma unroll
        for (int r = 0; r < 4; ++r) {
            float v = c[r] + bias;
            size_t o = (size_t)(node0 + quad * 4 + r) * 128 + ct * 16 + m;
            if (f32) ((float*)outraw)[o] = v;
            else     outraw[o] = f2b(v);
        }
    }
}

// ================= host =================
extern "C" void kernel_launch(void* const* d_in, const int* in_sizes, int n_in,
                              void* d_out, int out_size, void* d_ws, size_t ws_size,
                              hipStream_t stream) {
    const uint16_t* x    = (const uint16_t*)d_in[0];
    const int*      eidx = (const int*)     d_in[1];
    const uint16_t* ew   = (const uint16_t*)d_in[2];
    const uint16_t* w1   = (const uint16_t*)d_in[3];
    const uint16_t* b1   = (const uint16_t*)d_in[4];
    const uint16_t* w2   = (const uint16_t*)d_in[5];
    const uint16_t* b2   = (const uint16_t*)d_in[6];
    const uint16_t* eps  = (const uint16_t*)d_in[7];
    uint16_t*       out  = (uint16_t*)d_out;
    int* ws = (int*)d_ws;

    // zero node counters + overflow counter (graph-capture-safe async memset)
    hipMemsetAsync((char*)d_ws + (size_t)CNT_OFF * 4, 0,
                   (size_t)(NN + 1) * 4, stream);
    prep_fill_kernel<<<FILL_BLKS + PX_BLKS + PW_BLKS, 256, 0, stream>>>(
        x, eidx, ew, w1, w2, ws);
    gmlp_kernel<<<NN / 16, 256, 0, stream>>>(x, eidx, b1, b2, eps, ws, out);
}